// Round 1
// 1685.671 us; speedup vs baseline: 1.2393x; 1.2393x over previous
//
#include <hip/hip_runtime.h>
#include <cstddef>

#define HIDc 768
#define SLEN 2048
#define BB 4
#define NH 6
#define DH 64
#define AHSc 384
#define KW 9
#define BS_TOT 8192
#define HALFc 384

typedef __attribute__((ext_vector_type(4))) float f32x4;
typedef __attribute__((ext_vector_type(8))) short short8v;

__device__ __forceinline__ unsigned short f2bf(float f) {
    unsigned int u = __float_as_uint(f);
    unsigned int r = u + 0x7fffu + ((u >> 16) & 1u);
    return (unsigned short)(r >> 16);
}
__device__ __forceinline__ float bf2f(unsigned short h) {
    return __uint_as_float(((unsigned int)h) << 16);
}

// ---------------- generic tiled fp32 GEMM: C[M,N] = A[M,Kd]@B[Kd,N] + bias ----------------
// A row-major (lda), B row-major (ldb), C row-major (ldc) with column offset coff.
// Tiles: 64x64, BK=16, 256 threads, 4x4 micro-tile per thread.
__global__ __launch_bounds__(256)
void gemm64(const float* __restrict__ A, const float* __restrict__ Bm,
            const float* __restrict__ bias, float* __restrict__ C,
            int Kd, int lda, int ldb, int ldc, int coff)
{
    __shared__ float As[16][65];   // padded: conflict-free transposed store
    __shared__ float Bs[16][64];
    const int tid = threadIdx.x;
    const int tx = tid & 15, ty = tid >> 4;
    const int row0 = blockIdx.y * 64;
    const int col0 = blockIdx.x * 64;
    float acc[4][4] = {};
    for (int kt = 0; kt < Kd; kt += 16) {
#pragma unroll
        for (int i = 0; i < 4; ++i) {
            int idx = tid + i * 256;
            int r = idx >> 4, c = idx & 15;
            As[c][r] = A[(size_t)(row0 + r) * lda + kt + c];
        }
#pragma unroll
        for (int i = 0; i < 4; ++i) {
            int idx = tid + i * 256;
            int r = idx >> 6, c = idx & 63;
            Bs[r][c] = Bm[(size_t)(kt + r) * ldb + col0 + c];
        }
        __syncthreads();
#pragma unroll
        for (int kk = 0; kk < 16; ++kk) {
            float a[4], b[4];
#pragma unroll
            for (int i = 0; i < 4; ++i) a[i] = As[kk][ty * 4 + i];
#pragma unroll
            for (int j = 0; j < 4; ++j) b[j] = Bs[kk][tx * 4 + j];
#pragma unroll
            for (int i = 0; i < 4; ++i)
#pragma unroll
                for (int j = 0; j < 4; ++j) acc[i][j] += a[i] * b[j];
        }
        __syncthreads();
    }
#pragma unroll
    for (int i = 0; i < 4; ++i) {
        int r = row0 + ty * 4 + i;
#pragma unroll
        for (int j = 0; j < 4; ++j) {
            int c = col0 + tx * 4 + j;
            C[(size_t)r * ldc + coff + c] = acc[i][j] + bias[c];
        }
    }
}

// ---------------- depthwise conv over sequence, output [B,S,HID] ----------------
__global__ __launch_bounds__(256)
void dwconv_kernel(const float* __restrict__ x, const float* __restrict__ kern,
                   float* __restrict__ dwT)
{
    int idx = blockIdx.x * 256 + threadIdx.x;   // over BS_TOT*HID
    int c = idx % HIDc;
    int bs = idx / HIDc;
    int b = bs / SLEN, s = bs % SLEN;
    float acc = 0.f;
#pragma unroll
    for (int t = 0; t < KW; ++t) {
        int ss = s + t - KW / 2;
        if (ss >= 0 && ss < SLEN)
            acc += x[(size_t)(b * SLEN + ss) * HIDc + c] * kern[c * KW + t];
    }
    dwT[idx] = acc;
}

// ---------------- transpose pw_kernel [AHS,HID] -> [HID,AHS] ----------------
__global__ __launch_bounds__(256)
void transpose_pw(const float* __restrict__ pw, float* __restrict__ pwT)
{
    int idx = blockIdx.x * 256 + threadIdx.x;   // over AHS*HID
    int o = idx / HIDc, c = idx % HIDc;
    pwT[c * AHSc + o] = pw[idx];
}

// ---------------- fused conv-attention path ----------------
// per (b,s): conv_attn = ks_out*q; filt = conv_attn@Wak+bak; softmax over 9 taps;
// conv_out[h*64+d] = sum_k v[s+k-4, h*64+d] * filt[h,k]
__global__ __launch_bounds__(384)
void convattn_kernel(const float* __restrict__ ksout, const float* __restrict__ q,
                     const float* __restrict__ v, const float* __restrict__ Wak,
                     const float* __restrict__ bak, float* __restrict__ conv_out)
{
    __shared__ float ca[AHSc];
    __shared__ float part[7][54];
    __shared__ float filt[54];
    int bs = blockIdx.x;
    int b = bs / SLEN, s = bs % SLEN;
    int t = threadIdx.x;
    ca[t] = ksout[(size_t)bs * AHSc + t] * q[(size_t)bs * AHSc + t];
    __syncthreads();
    if (t < 378) {
        int o = t % 54, g = t / 54;
        int c0 = g * 55, c1 = c0 + 55 > AHSc ? AHSc : c0 + 55;
        float acc = 0.f;
        for (int c = c0; c < c1; ++c) acc += ca[c] * Wak[c * 54 + o];
        part[g][o] = acc;
    }
    __syncthreads();
    if (t < 54) {
        float acc = bak[t];
#pragma unroll
        for (int g = 0; g < 7; ++g) acc += part[g][t];
        filt[t] = acc;
    }
    __syncthreads();
    if (t < NH) {
        float m = -1e30f;
#pragma unroll
        for (int k = 0; k < KW; ++k) m = fmaxf(m, filt[t * KW + k]);
        float sum = 0.f; float e[KW];
#pragma unroll
        for (int k = 0; k < KW; ++k) { e[k] = __expf(filt[t * KW + k] - m); sum += e[k]; }
        float inv = 1.f / sum;
#pragma unroll
        for (int k = 0; k < KW; ++k) filt[t * KW + k] = e[k] * inv;
    }
    __syncthreads();
    int h = t >> 6;
    float acc = 0.f;
#pragma unroll
    for (int k = 0; k < KW; ++k) {
        int ss = s + k - KW / 2;
        if (ss >= 0 && ss < SLEN)
            acc += v[(size_t)(b * SLEN + ss) * AHSc + t] * filt[h * KW + k];
    }
    conv_out[(size_t)bs * AHSc + t] = acc;
}

// ---------------- attention scores via bf16x3 MFMA ----------------
// Per block: 128x128 output tile of S = (Q @ K^T)/8 + mask for one (b,h).
// Q,K split into bf16 hi+lo; 3 MFMA passes (hi*hi + hi*lo + lo*hi) give
// fp32-grade precision (dropped lo*lo term ~2^-18 relative).
// LDS tiles [128][64] bf16, 16B chunks XOR-swizzled by (row&7) so the
// stride-128B rows don't cause 32-way ds_read_b128 bank conflicts.
__global__ __launch_bounds__(256)
void scores_mfma(const float* __restrict__ qm, const float* __restrict__ km,
                 const float* __restrict__ mask, float* __restrict__ scores)
{
    __shared__ unsigned short Qhi[128][64];
    __shared__ unsigned short Qlo[128][64];
    __shared__ unsigned short Khi[128][64];
    __shared__ unsigned short Klo[128][64];
    const int bh = blockIdx.z;
    const int b = bh / NH, h = bh % NH;
    const int q0 = blockIdx.y * 128, k0 = blockIdx.x * 128;
    const int tid = threadIdx.x;

    // stage: per matrix 128 rows x 8 chunks (8 floats each) -> 1024 tasks, 4/thread
#pragma unroll
    for (int i = 0; i < 4; ++i) {
        int id = tid + i * 256;
        int row = id >> 3, ch = id & 7;
        int pch = ch ^ (row & 7);                 // swizzled 16B chunk index
        const float* sq = qm + (size_t)(b * SLEN + q0 + row) * AHSc + h * 64 + ch * 8;
        const float* sk = km + (size_t)(b * SLEN + k0 + row) * AHSc + h * 64 + ch * 8;
        f32x4 qa = *(const f32x4*)sq;
        f32x4 qb = *(const f32x4*)(sq + 4);
        f32x4 ka = *(const f32x4*)sk;
        f32x4 kb = *(const f32x4*)(sk + 4);
        short8v qh, ql, kh, kl;
#pragma unroll
        for (int j = 0; j < 4; ++j) {
            unsigned short t0 = f2bf(qa[j]);
            qh[j] = (short)t0; ql[j] = (short)f2bf(qa[j] - bf2f(t0));
            unsigned short t1 = f2bf(qb[j]);
            qh[j + 4] = (short)t1; ql[j + 4] = (short)f2bf(qb[j] - bf2f(t1));
            unsigned short t2 = f2bf(ka[j]);
            kh[j] = (short)t2; kl[j] = (short)f2bf(ka[j] - bf2f(t2));
            unsigned short t3 = f2bf(kb[j]);
            kh[j + 4] = (short)t3; kl[j + 4] = (short)f2bf(kb[j] - bf2f(t3));
        }
        *(short8v*)&Qhi[row][pch * 8] = qh;
        *(short8v*)&Qlo[row][pch * 8] = ql;
        *(short8v*)&Khi[row][pch * 8] = kh;
        *(short8v*)&Klo[row][pch * 8] = kl;
    }
    __syncthreads();

    const int l = tid & 63, w = tid >> 6;
    const int wr0 = (w & 1) * 64, wc0 = (w >> 1) * 64;   // wave's 64x64 sub-tile
    const int lr = l & 15, lk = l >> 4;
    f32x4 acc[4][4] = {};
#pragma unroll
    for (int kc = 0; kc < 2; ++kc) {
        const int lch = kc * 4 + lk;                      // logical 16B chunk along k
        short8v ah[4], al[4], bhv[4], blv[4];
#pragma unroll
        for (int m = 0; m < 4; ++m) {
            int row = wr0 + m * 16 + lr;
            int pch = lch ^ (row & 7);
            ah[m] = *(const short8v*)&Qhi[row][pch * 8];
            al[m] = *(const short8v*)&Qlo[row][pch * 8];
        }
#pragma unroll
        for (int n = 0; n < 4; ++n) {
            int row = wc0 + n * 16 + lr;
            int pch = lch ^ (row & 7);
            bhv[n] = *(const short8v*)&Khi[row][pch * 8];
            blv[n] = *(const short8v*)&Klo[row][pch * 8];
        }
#pragma unroll
        for (int m = 0; m < 4; ++m)
#pragma unroll
            for (int n = 0; n < 4; ++n) {
                acc[m][n] = __builtin_amdgcn_mfma_f32_16x16x32_bf16(ah[m], bhv[n], acc[m][n], 0, 0, 0);
                acc[m][n] = __builtin_amdgcn_mfma_f32_16x16x32_bf16(ah[m], blv[n], acc[m][n], 0, 0, 0);
                acc[m][n] = __builtin_amdgcn_mfma_f32_16x16x32_bf16(al[m], bhv[n], acc[m][n], 0, 0, 0);
            }
    }

    // epilogue: C/D layout col=lane&15, row=(lane>>4)*4+reg (m89-verified)
#pragma unroll
    for (int n = 0; n < 4; ++n) {
        int kcl = k0 + wc0 + n * 16 + lr;
        float mk = mask[b * SLEN + kcl];
#pragma unroll
        for (int m = 0; m < 4; ++m) {
            int qr0 = q0 + wr0 + m * 16 + lk * 4;
#pragma unroll
            for (int r = 0; r < 4; ++r) {
                scores[((size_t)bh * SLEN + qr0 + r) * SLEN + kcl] = acc[m][n][r] * 0.125f + mk;
            }
        }
    }
}

// ---------------- row softmax stats: m and 1/l per score row ----------------
__global__ __launch_bounds__(256)
void rowstats_kernel(const float* __restrict__ scores, float* __restrict__ stats)
{
    __shared__ float red[256];
    int row = blockIdx.x;               // bh*2048 + qpos
    const float* sc = scores + (size_t)row * SLEN;
    int t = threadIdx.x;
    float vals[8]; float lm = -1e30f;
#pragma unroll
    for (int i = 0; i < 8; ++i) { vals[i] = sc[t + i * 256]; lm = fmaxf(lm, vals[i]); }
    red[t] = lm; __syncthreads();
    for (int s2 = 128; s2 > 0; s2 >>= 1) {
        if (t < s2) red[t] = fmaxf(red[t], red[t + s2]);
        __syncthreads();
    }
    float m = red[0]; __syncthreads();
    float ls = 0.f;
#pragma unroll
    for (int i = 0; i < 8; ++i) ls += __expf(vals[i] - m);
    red[t] = ls; __syncthreads();
    for (int s2 = 128; s2 > 0; s2 >>= 1) {
        if (t < s2) red[t] += red[t + s2];
        __syncthreads();
    }
    if (t == 0) { stats[row * 2] = m; stats[row * 2 + 1] = 1.f / red[0]; }
}

// ---------------- PV: attn_out[64-row tile] = softmax(scores)@V ----------------
__global__ __launch_bounds__(256)
void pv_kernel(const float* __restrict__ scores, const float* __restrict__ stats,
               const float* __restrict__ v, float* __restrict__ attn_out)
{
    __shared__ float Ps[64][65];   // [k][row], transposed with pad
    __shared__ float Vs[64][65];   // [k][d]
    int bh = blockIdx.z; int b = bh / NH, h = bh % NH;
    int q0 = blockIdx.y * 64;
    int tid = threadIdx.x;
    int tx = tid & 15, ty = tid >> 4;
    float acc[4][4] = {};
    const float* srow = scores + ((size_t)bh * SLEN + q0) * SLEN;
    for (int kt = 0; kt < SLEN; kt += 64) {
#pragma unroll
        for (int i = 0; i < 16; ++i) {
            int idx = tid + i * 256;
            int r = idx >> 6, c = idx & 63;
            float mval = stats[(bh * SLEN + q0 + r) * 2 + 0];
            float linv = stats[(bh * SLEN + q0 + r) * 2 + 1];
            Ps[c][r] = __expf(srow[(size_t)r * SLEN + kt + c] - mval) * linv;
            Vs[r][c] = v[(size_t)(b * SLEN + kt + r) * AHSc + h * 64 + c];
        }
        __syncthreads();
#pragma unroll
        for (int kk = 0; kk < 64; ++kk) {
            float a[4], bb[4];
#pragma unroll
            for (int i = 0; i < 4; ++i) a[i] = Ps[kk][ty * 4 + i];
#pragma unroll
            for (int j = 0; j < 4; ++j) bb[j] = Vs[kk][tx * 4 + j];
#pragma unroll
            for (int i = 0; i < 4; ++i)
#pragma unroll
                for (int j = 0; j < 4; ++j) acc[i][j] += a[i] * bb[j];
        }
        __syncthreads();
    }
#pragma unroll
    for (int i = 0; i < 4; ++i)
#pragma unroll
        for (int j = 0; j < 4; ++j)
            attn_out[(size_t)(b * SLEN + q0 + ty * 4 + i) * AHSc + h * 64 + tx * 4 + j] = acc[i][j];
}

extern "C" void kernel_launch(void* const* d_in, const int* in_sizes, int n_in,
                              void* d_out, int out_size, void* d_ws, size_t ws_size,
                              hipStream_t stream)
{
    const float* hidden = (const float*)d_in[0];
    const float* mask   = (const float*)d_in[1];
    const float* Wq  = (const float*)d_in[2];
    const float* bq  = (const float*)d_in[3];
    const float* Wk  = (const float*)d_in[4];
    const float* bk  = (const float*)d_in[5];
    const float* Wv  = (const float*)d_in[6];
    const float* bv  = (const float*)d_in[7];
    const float* dwk = (const float*)d_in[8];
    const float* pw  = (const float*)d_in[9];
    const float* sepb= (const float*)d_in[10];
    const float* Wak = (const float*)d_in[11];
    const float* bak = (const float*)d_in[12];
    const float* Wsl = (const float*)d_in[13];
    const float* bsl = (const float*)d_in[14];
    const float* Wcl = (const float*)d_in[15];
    const float* bcl = (const float*)d_in[16];

    float* out = (float*)d_out;
    float* ctx_out  = out;                     // [8192,768]
    float* attn_out = out + 6291456;           // [8192,384]
    float* scores   = out + 9437184;           // [24,2048,2048]

    float* ws = (float*)d_ws;
    float* q        = ws;                      // 3145728
    float* kbuf     = ws + 3145728;            // 3145728
    float* vbuf     = ws + 6291456;            // 3145728
    float* dwT      = ws + 9437184;            // 6291456 (dead after pointwise GEMM)
    float* conv_out = ws + 9437184;            // 3145728 (reuses dwT region)
    float* stats    = ws + 12582912;           // 98304
    float* ksout    = ws + 15728640;           // 3145728
    float* pwT      = ws + 18874368;           // 294912
    (void)in_sizes; (void)n_in; (void)out_size; (void)ws_size;

    dim3 blk(256);
    dim3 gemm_grid(AHSc / 64, BS_TOT / 64);    // (6,128)

    // QKV projections
    gemm64<<<gemm_grid, blk, 0, stream>>>(hidden, Wq, bq, q,    HIDc, HIDc, AHSc, AHSc, 0);
    gemm64<<<gemm_grid, blk, 0, stream>>>(hidden, Wk, bk, kbuf, HIDc, HIDc, AHSc, AHSc, 0);
    gemm64<<<gemm_grid, blk, 0, stream>>>(hidden, Wv, bv, vbuf, HIDc, HIDc, AHSc, AHSc, 0);

    // separable conv: depthwise then pointwise
    dwconv_kernel<<<BS_TOT * HIDc / 256, blk, 0, stream>>>(hidden, dwk, dwT);
    transpose_pw<<<AHSc * HIDc / 256, blk, 0, stream>>>(pw, pwT);
    gemm64<<<gemm_grid, blk, 0, stream>>>(dwT, pwT, sepb, ksout, HIDc, HIDc, AHSc, AHSc, 0);

    // conv-attention path -> conv_out
    convattn_kernel<<<dim3(BS_TOT), dim3(384), 0, stream>>>(ksout, q, vbuf, Wak, bak, conv_out);

    // self-attention: scores (bf16x3 MFMA), softmax stats, PV
    scores_mfma<<<dim3(SLEN / 128, SLEN / 128, BB * NH), blk, 0, stream>>>(q, kbuf, mask, scores);
    rowstats_kernel<<<dim3(BB * NH * SLEN), blk, 0, stream>>>(scores, stats);
    pv_kernel<<<dim3(1, SLEN / 64, BB * NH), blk, 0, stream>>>(scores, stats, vbuf, attn_out);

    // final mix: ctx = [attn_out@Wsl+bsl , conv_out@Wcl+bcl]
    gemm64<<<gemm_grid, blk, 0, stream>>>(attn_out, Wsl, bsl, ctx_out, AHSc, AHSc, HALFc, HIDc, 0);
    gemm64<<<gemm_grid, blk, 0, stream>>>(conv_out, Wcl, bcl, ctx_out, AHSc, AHSc, HALFc, HIDc, HALFc);
}

// Round 3
// 1152.749 us; speedup vs baseline: 1.8122x; 1.4623x over previous
//
#include <hip/hip_runtime.h>
#include <cstddef>

#define HIDc 768
#define SLEN 2048
#define BB 4
#define NH 6
#define AHSc 384
#define KW 9
#define BS_TOT 8192
#define HALFc 384

typedef unsigned short u16;
typedef __attribute__((ext_vector_type(4))) float f32x4;
typedef __attribute__((ext_vector_type(8))) short short8v;
typedef __attribute__((ext_vector_type(4))) unsigned short u16x4;

__device__ __forceinline__ u16 f2bf(float f) {
    unsigned int u = __float_as_uint(f);
    return (u16)((u + 0x7fffu + ((u >> 16) & 1u)) >> 16);
}
__device__ __forceinline__ float bf2f(u16 h) {
    return __uint_as_float(((unsigned int)h) << 16);
}

// descriptor for one GEMM problem instance (selected by blockIdx.z)
struct GSet {
    const float* A;                   // [M][K] fp32 activation
    const u16* Bh; const u16* Bl;     // B^T [N][K] bf16 hi/lo planes
    const float* bias; float* C; int coff;
};

// ---------------- split f32 -> bf16 hi/lo planes (elementwise, no transpose) ----------------
__global__ __launch_bounds__(256)
void split_bf16(const float* __restrict__ x, u16* __restrict__ hi,
                u16* __restrict__ lo, int n4)
{
    int i = blockIdx.x * 256 + threadIdx.x;
    if (i >= n4) return;
    f32x4 v = ((const f32x4*)x)[i];
    u16x4 h, l;
#pragma unroll
    for (int j = 0; j < 4; ++j) {
        u16 hh = f2bf(v[j]);
        h[j] = hh; l[j] = f2bf(v[j] - bf2f(hh));
    }
    ((u16x4*)hi)[i] = h;
    ((u16x4*)lo)[i] = l;
}

// ---------------- transpose+split weight: W[K][N] -> Wt hi/lo [N][K] ----------------
__global__ __launch_bounds__(256)
void wsplit_t(const float* __restrict__ W, u16* __restrict__ th,
              u16* __restrict__ tl, int K, int N)
{
    int idx = blockIdx.x * 256 + threadIdx.x;   // over K*N
    int k = idx / N, n = idx % N;
    float v = W[idx];
    u16 h = f2bf(v);
    th[(size_t)n * K + k] = h;
    tl[(size_t)n * K + k] = f2bf(v - bf2f(h));
}

// ---------------- depthwise conv over sequence, output fp32 [B*S][HID] ----------------
__global__ __launch_bounds__(256)
void dwconv_kernel(const float* __restrict__ x, const float* __restrict__ kern,
                   float* __restrict__ dwT)
{
    int idx = blockIdx.x * 256 + threadIdx.x;   // over BS_TOT*HID
    int c = idx % HIDc;
    int bs = idx / HIDc;
    int b = bs / SLEN, s = bs % SLEN;
    float acc = 0.f;
#pragma unroll
    for (int t = 0; t < KW; ++t) {
        int ss = s + t - KW / 2;
        if (ss >= 0 && ss < SLEN)
            acc += x[(size_t)(b * SLEN + ss) * HIDc + c] * kern[c * KW + t];
    }
    dwT[idx] = acc;
}

// ---------------- V transpose+split: vbuf [B,S,H*64] -> vt hi/lo [B*H, 64, S] ----------------
__global__ __launch_bounds__(256)
void vt_split(const float* __restrict__ v, u16* __restrict__ th, u16* __restrict__ tl)
{
    __shared__ float t[64][65];
    int s0 = blockIdx.x * 64;
    int bh = blockIdx.y; int b = bh / NH, h = bh % NH;
    int tid = threadIdx.x;
#pragma unroll
    for (int i = 0; i < 16; ++i) {
        int idx = tid + i * 256;
        int r = idx >> 6, c = idx & 63;
        t[r][c] = v[(size_t)(b * SLEN + s0 + r) * AHSc + h * 64 + c];
    }
    __syncthreads();
#pragma unroll
    for (int i = 0; i < 16; ++i) {
        int idx = tid + i * 256;
        int d = idx >> 6, s = idx & 63;
        float val = t[s][d];
        u16 hh = f2bf(val);
        size_t o = ((size_t)bh * 64 + d) * SLEN + s0 + s;
        th[o] = hh;
        tl[o] = f2bf(val - bf2f(hh));
    }
}

// ---------------- bf16x3 MFMA GEMM: C[M][*] = A(fp32)@Bt + bias ----------------
// 128x128 tile, BK=64, 256 threads = 4 waves of 64x64 sub-tiles.
// A is fp32, split to bf16 hi/lo during LDS staging (pattern proven in scores_mfma).
// B pre-split planes. 16B-chunk XOR swizzle (ch ^= row&7) on all LDS tiles.
__global__ __launch_bounds__(256)
void gemm_mfma(GSet s0, GSet s1, GSet s2, int K, int ldc)
{
    __shared__ u16 Ash[128][64];
    __shared__ u16 Asl[128][64];
    __shared__ u16 Bsh[128][64];
    __shared__ u16 Bsl[128][64];
    int z = blockIdx.z;
    const GSet S = z == 0 ? s0 : (z == 1 ? s1 : s2);
    const int row0 = blockIdx.y * 128;
    const int col0 = blockIdx.x * 128;
    const int tid = threadIdx.x;
    const int l = tid & 63, w = tid >> 6;
    const int wr0 = (w & 1) * 64, wc0 = (w >> 1) * 64;
    const int lr = l & 15, lk = l >> 4;
    f32x4 acc[4][4] = {};
    for (int kt = 0; kt < K; kt += 64) {
#pragma unroll
        for (int i = 0; i < 4; ++i) {
            int id = tid + i * 256;             // 1024 tasks: 128 rows x 8 chunks
            int r = id >> 3, ch = id & 7;
            int pch = ch ^ (r & 7);
            const float* ap = S.A + (size_t)(row0 + r) * K + kt + ch * 8;
            f32x4 a0 = *(const f32x4*)ap;
            f32x4 a1 = *(const f32x4*)(ap + 4);
            short8v ah, al;
#pragma unroll
            for (int j = 0; j < 4; ++j) {
                u16 h0 = f2bf(a0[j]);
                ah[j] = (short)h0; al[j] = (short)f2bf(a0[j] - bf2f(h0));
                u16 h1 = f2bf(a1[j]);
                ah[j + 4] = (short)h1; al[j + 4] = (short)f2bf(a1[j] - bf2f(h1));
            }
            *(short8v*)&Ash[r][pch * 8] = ah;
            *(short8v*)&Asl[r][pch * 8] = al;
            size_t gb = (size_t)(col0 + r) * K + kt + ch * 8;
            *(short8v*)&Bsh[r][pch * 8] = *(const short8v*)&S.Bh[gb];
            *(short8v*)&Bsl[r][pch * 8] = *(const short8v*)&S.Bl[gb];
        }
        __syncthreads();
#pragma unroll
        for (int kc = 0; kc < 2; ++kc) {
            int lch = kc * 4 + lk;
            short8v ah[4], al[4];
#pragma unroll
            for (int m = 0; m < 4; ++m) {
                int r = wr0 + m * 16 + lr;
                int pch = lch ^ (r & 7);
                ah[m] = *(const short8v*)&Ash[r][pch * 8];
                al[m] = *(const short8v*)&Asl[r][pch * 8];
            }
#pragma unroll
            for (int n = 0; n < 4; ++n) {
                int r = wc0 + n * 16 + lr;
                int pch = lch ^ (r & 7);
                short8v bh = *(const short8v*)&Bsh[r][pch * 8];
                short8v bl = *(const short8v*)&Bsl[r][pch * 8];
#pragma unroll
                for (int m = 0; m < 4; ++m) {
                    acc[m][n] = __builtin_amdgcn_mfma_f32_16x16x32_bf16(ah[m], bh, acc[m][n], 0, 0, 0);
                    acc[m][n] = __builtin_amdgcn_mfma_f32_16x16x32_bf16(ah[m], bl, acc[m][n], 0, 0, 0);
                    acc[m][n] = __builtin_amdgcn_mfma_f32_16x16x32_bf16(al[m], bh, acc[m][n], 0, 0, 0);
                }
            }
        }
        __syncthreads();
    }
#pragma unroll
    for (int n = 0; n < 4; ++n) {
        int c = col0 + wc0 + n * 16 + lr;
        float bb = S.bias[c];
#pragma unroll
        for (int m = 0; m < 4; ++m) {
            int r0 = row0 + wr0 + m * 16 + lk * 4;
#pragma unroll
            for (int r = 0; r < 4; ++r)
                S.C[(size_t)(r0 + r) * ldc + S.coff + c] = acc[m][n][r] + bb;
        }
    }
}

// ---------------- fused conv-attention path ----------------
__global__ __launch_bounds__(384)
void convattn_kernel(const float* __restrict__ ksout, const float* __restrict__ q,
                     const float* __restrict__ v, const float* __restrict__ Wak,
                     const float* __restrict__ bak, float* __restrict__ conv_out)
{
    __shared__ float ca[AHSc];
    __shared__ float part[7][54];
    __shared__ float filt[54];
    int bs = blockIdx.x;
    int b = bs / SLEN, s = bs % SLEN;
    int t = threadIdx.x;
    ca[t] = ksout[(size_t)bs * AHSc + t] * q[(size_t)bs * AHSc + t];
    __syncthreads();
    if (t < 378) {
        int o = t % 54, g = t / 54;
        int c0 = g * 55, c1 = c0 + 55 > AHSc ? AHSc : c0 + 55;
        float acc = 0.f;
        for (int c = c0; c < c1; ++c) acc += ca[c] * Wak[c * 54 + o];
        part[g][o] = acc;
    }
    __syncthreads();
    if (t < 54) {
        float acc = bak[t];
#pragma unroll
        for (int g = 0; g < 7; ++g) acc += part[g][t];
        filt[t] = acc;
    }
    __syncthreads();
    if (t < NH) {
        float m = -1e30f;
#pragma unroll
        for (int k = 0; k < KW; ++k) m = fmaxf(m, filt[t * KW + k]);
        float sum = 0.f; float e[KW];
#pragma unroll
        for (int k = 0; k < KW; ++k) { e[k] = __expf(filt[t * KW + k] - m); sum += e[k]; }
        float inv = 1.f / sum;
#pragma unroll
        for (int k = 0; k < KW; ++k) filt[t * KW + k] = e[k] * inv;
    }
    __syncthreads();
    int h = t >> 6;
    float acc = 0.f;
#pragma unroll
    for (int k = 0; k < KW; ++k) {
        int ss = s + k - KW / 2;
        if (ss >= 0 && ss < SLEN)
            acc += v[(size_t)(b * SLEN + ss) * AHSc + t] * filt[h * KW + k];
    }
    conv_out[(size_t)bs * AHSc + t] = acc;
}

// ---------------- attention scores via bf16x3 MFMA ----------------
__global__ __launch_bounds__(256)
void scores_mfma(const float* __restrict__ qm, const float* __restrict__ km,
                 const float* __restrict__ mask, float* __restrict__ scores)
{
    __shared__ u16 Qhi[128][64];
    __shared__ u16 Qlo[128][64];
    __shared__ u16 Khi[128][64];
    __shared__ u16 Klo[128][64];
    const int bh = blockIdx.z;
    const int b = bh / NH, h = bh % NH;
    const int q0 = blockIdx.y * 128, k0 = blockIdx.x * 128;
    const int tid = threadIdx.x;
#pragma unroll
    for (int i = 0; i < 4; ++i) {
        int id = tid + i * 256;
        int row = id >> 3, ch = id & 7;
        int pch = ch ^ (row & 7);
        const float* sq = qm + (size_t)(b * SLEN + q0 + row) * AHSc + h * 64 + ch * 8;
        const float* sk = km + (size_t)(b * SLEN + k0 + row) * AHSc + h * 64 + ch * 8;
        f32x4 qa = *(const f32x4*)sq;
        f32x4 qb = *(const f32x4*)(sq + 4);
        f32x4 ka = *(const f32x4*)sk;
        f32x4 kb = *(const f32x4*)(sk + 4);
        short8v qh, ql, kh, kl;
#pragma unroll
        for (int j = 0; j < 4; ++j) {
            u16 t0 = f2bf(qa[j]);
            qh[j] = (short)t0; ql[j] = (short)f2bf(qa[j] - bf2f(t0));
            u16 t1 = f2bf(qb[j]);
            qh[j + 4] = (short)t1; ql[j + 4] = (short)f2bf(qb[j] - bf2f(t1));
            u16 t2 = f2bf(ka[j]);
            kh[j] = (short)t2; kl[j] = (short)f2bf(ka[j] - bf2f(t2));
            u16 t3 = f2bf(kb[j]);
            kh[j + 4] = (short)t3; kl[j + 4] = (short)f2bf(kb[j] - bf2f(t3));
        }
        *(short8v*)&Qhi[row][pch * 8] = qh;
        *(short8v*)&Qlo[row][pch * 8] = ql;
        *(short8v*)&Khi[row][pch * 8] = kh;
        *(short8v*)&Klo[row][pch * 8] = kl;
    }
    __syncthreads();

    const int l = tid & 63, w = tid >> 6;
    const int wr0 = (w & 1) * 64, wc0 = (w >> 1) * 64;
    const int lr = l & 15, lk = l >> 4;
    f32x4 acc[4][4] = {};
#pragma unroll
    for (int kc = 0; kc < 2; ++kc) {
        const int lch = kc * 4 + lk;
        short8v ah[4], al[4], bhv[4], blv[4];
#pragma unroll
        for (int m = 0; m < 4; ++m) {
            int row = wr0 + m * 16 + lr;
            int pch = lch ^ (row & 7);
            ah[m] = *(const short8v*)&Qhi[row][pch * 8];
            al[m] = *(const short8v*)&Qlo[row][pch * 8];
        }
#pragma unroll
        for (int n = 0; n < 4; ++n) {
            int row = wc0 + n * 16 + lr;
            int pch = lch ^ (row & 7);
            bhv[n] = *(const short8v*)&Khi[row][pch * 8];
            blv[n] = *(const short8v*)&Klo[row][pch * 8];
        }
#pragma unroll
        for (int m = 0; m < 4; ++m)
#pragma unroll
            for (int n = 0; n < 4; ++n) {
                acc[m][n] = __builtin_amdgcn_mfma_f32_16x16x32_bf16(ah[m], bhv[n], acc[m][n], 0, 0, 0);
                acc[m][n] = __builtin_amdgcn_mfma_f32_16x16x32_bf16(ah[m], blv[n], acc[m][n], 0, 0, 0);
                acc[m][n] = __builtin_amdgcn_mfma_f32_16x16x32_bf16(al[m], bhv[n], acc[m][n], 0, 0, 0);
            }
    }
#pragma unroll
    for (int n = 0; n < 4; ++n) {
        int kcl = k0 + wc0 + n * 16 + lr;
        float mk = mask[b * SLEN + kcl];
#pragma unroll
        for (int m = 0; m < 4; ++m) {
            int qr0 = q0 + wr0 + m * 16 + lk * 4;
#pragma unroll
            for (int r = 0; r < 4; ++r) {
                scores[((size_t)bh * SLEN + qr0 + r) * SLEN + kcl] = acc[m][n][r] * 0.125f + mk;
            }
        }
    }
}

// ---------------- row softmax stats: m and 1/l per score row ----------------
__global__ __launch_bounds__(256)
void rowstats_kernel(const float* __restrict__ scores, float* __restrict__ stats)
{
    __shared__ float red[256];
    int row = blockIdx.x;               // bh*2048 + qpos
    const float* sc = scores + (size_t)row * SLEN;
    int t = threadIdx.x;
    float vals[8]; float lm = -1e30f;
#pragma unroll
    for (int i = 0; i < 8; ++i) { vals[i] = sc[t + i * 256]; lm = fmaxf(lm, vals[i]); }
    red[t] = lm; __syncthreads();
    for (int s2 = 128; s2 > 0; s2 >>= 1) {
        if (t < s2) red[t] = fmaxf(red[t], red[t + s2]);
        __syncthreads();
    }
    float m = red[0]; __syncthreads();
    float ls = 0.f;
#pragma unroll
    for (int i = 0; i < 8; ++i) ls += __expf(vals[i] - m);
    red[t] = ls; __syncthreads();
    for (int s2 = 128; s2 > 0; s2 >>= 1) {
        if (t < s2) red[t] += red[t + s2];
        __syncthreads();
    }
    if (t == 0) { stats[row * 2] = m; stats[row * 2 + 1] = 1.f / red[0]; }
}

// ---------------- PV via bf16x3 MFMA: attn_out = softmax(scores)@V ----------------
__global__ __launch_bounds__(256)
void pv_mfma(const float* __restrict__ scores, const float* __restrict__ stats,
             const u16* __restrict__ vth, const u16* __restrict__ vtl,
             float* __restrict__ attn_out)
{
    __shared__ u16 Ph[64][64];
    __shared__ u16 Pl[64][64];
    __shared__ u16 Vh[64][64];
    __shared__ u16 Vl[64][64];
    const int q0 = blockIdx.x * 64;
    const int bh = blockIdx.y; const int b = bh / NH, h = bh % NH;
    const int tid = threadIdx.x;
    const int l = tid & 63, w = tid >> 6;
    const int wr0 = (w & 1) * 32, wc0 = (w >> 1) * 32;
    const int lr = l & 15, lk = l >> 4;
    f32x4 acc[2][2] = {};
    for (int kt = 0; kt < SLEN; kt += 64) {
#pragma unroll
        for (int i = 0; i < 2; ++i) {
            int id = tid + i * 256;             // 512 tasks: 64 rows x 8 chunks
            int r = id >> 3, ch = id & 7;
            int pch = ch ^ (r & 7);
            int grow = bh * SLEN + q0 + r;
            const float* sp = scores + (size_t)grow * SLEN + kt + ch * 8;
            float mv = stats[grow * 2], li = stats[grow * 2 + 1];
            f32x4 a = *(const f32x4*)sp;
            f32x4 c = *(const f32x4*)(sp + 4);
            short8v ph, pl;
#pragma unroll
            for (int j = 0; j < 4; ++j) {
                float p0 = __expf(a[j] - mv) * li;
                u16 h0 = f2bf(p0);
                ph[j] = (short)h0; pl[j] = (short)f2bf(p0 - bf2f(h0));
                float p1 = __expf(c[j] - mv) * li;
                u16 h1 = f2bf(p1);
                ph[j + 4] = (short)h1; pl[j + 4] = (short)f2bf(p1 - bf2f(h1));
            }
            *(short8v*)&Ph[r][pch * 8] = ph;
            *(short8v*)&Pl[r][pch * 8] = pl;
            size_t gv = ((size_t)bh * 64 + r) * SLEN + kt + ch * 8;
            *(short8v*)&Vh[r][pch * 8] = *(const short8v*)&vth[gv];
            *(short8v*)&Vl[r][pch * 8] = *(const short8v*)&vtl[gv];
        }
        __syncthreads();
#pragma unroll
        for (int kc = 0; kc < 2; ++kc) {
            int lch = kc * 4 + lk;
            short8v ah[2], al[2], bh2[2], bl2[2];
#pragma unroll
            for (int m = 0; m < 2; ++m) {
                int r = wr0 + m * 16 + lr;
                int pch = lch ^ (r & 7);
                ah[m] = *(const short8v*)&Ph[r][pch * 8];
                al[m] = *(const short8v*)&Pl[r][pch * 8];
            }
#pragma unroll
            for (int n = 0; n < 2; ++n) {
                int r = wc0 + n * 16 + lr;
                int pch = lch ^ (r & 7);
                bh2[n] = *(const short8v*)&Vh[r][pch * 8];
                bl2[n] = *(const short8v*)&Vl[r][pch * 8];
            }
#pragma unroll
            for (int m = 0; m < 2; ++m)
#pragma unroll
                for (int n = 0; n < 2; ++n) {
                    acc[m][n] = __builtin_amdgcn_mfma_f32_16x16x32_bf16(ah[m], bh2[n], acc[m][n], 0, 0, 0);
                    acc[m][n] = __builtin_amdgcn_mfma_f32_16x16x32_bf16(al[m], bh2[n], acc[m][n], 0, 0, 0);
                    acc[m][n] = __builtin_amdgcn_mfma_f32_16x16x32_bf16(ah[m], bl2[n], acc[m][n], 0, 0, 0);
                }
        }
        __syncthreads();
    }
#pragma unroll
    for (int n = 0; n < 2; ++n) {
        int c = wc0 + n * 16 + lr;
#pragma unroll
        for (int m = 0; m < 2; ++m) {
            int r0 = wr0 + m * 16 + lk * 4;
#pragma unroll
            for (int r = 0; r < 4; ++r)
                attn_out[(size_t)(b * SLEN + q0 + r0 + r) * AHSc + h * 64 + c] = acc[m][n][r];
        }
    }
}

extern "C" void kernel_launch(void* const* d_in, const int* in_sizes, int n_in,
                              void* d_out, int out_size, void* d_ws, size_t ws_size,
                              hipStream_t stream)
{
    const float* hidden = (const float*)d_in[0];
    const float* mask   = (const float*)d_in[1];
    const float* Wq  = (const float*)d_in[2];
    const float* bq  = (const float*)d_in[3];
    const float* Wk  = (const float*)d_in[4];
    const float* bk  = (const float*)d_in[5];
    const float* Wv  = (const float*)d_in[6];
    const float* bv  = (const float*)d_in[7];
    const float* dwk = (const float*)d_in[8];
    const float* pw  = (const float*)d_in[9];
    const float* sepb= (const float*)d_in[10];
    const float* Wak = (const float*)d_in[11];
    const float* bak = (const float*)d_in[12];
    const float* Wsl = (const float*)d_in[13];
    const float* bsl = (const float*)d_in[14];
    const float* Wcl = (const float*)d_in[15];
    const float* bcl = (const float*)d_in[16];

    float* out = (float*)d_out;
    float* ctx_out  = out;                     // [8192,768]
    float* attn_out = out + 6291456;           // [8192,384]
    float* scores   = out + 9437184;           // [24,2048,2048]

    // scratch inside the scores region: both buffers are fully consumed
    // before scores_mfma launches, which then overwrites the whole region.
    float* dwT   = scores;                     // [8192,768] fp32 scratch
    float* ksout = scores + 3145728;           // [8192,384] fp32 scratch

    float* ws = (float*)d_ws;                  // total 69.2 MB (< proven 76.7 MB)
    float* q        = ws;                      // 3,145,728
    float* kbuf     = ws + 3145728;
    float* vbuf     = ws + 6291456;
    float* conv_out = ws + 9437184;            // 3,145,728
    u16*   vt_h     = (u16*)(ws + 12582912);   // [24][64][2048] bf16
    u16*   vt_l     = (u16*)(ws + 14155776);
    float* stats    = ws + 15728640;           // 98,304
    u16*   WqT_h    = (u16*)(ws + 15826944);   // [384][768] bf16 each (147,456 fl)
    u16*   WqT_l    = (u16*)(ws + 15974400);
    u16*   WkT_h    = (u16*)(ws + 16121856);
    u16*   WkT_l    = (u16*)(ws + 16269312);
    u16*   WvT_h    = (u16*)(ws + 16416768);
    u16*   WvT_l    = (u16*)(ws + 16564224);
    u16*   pw_h     = (u16*)(ws + 16711680);   // [384][768] (pw already [N][K])
    u16*   pw_l     = (u16*)(ws + 16859136);
    u16*   WslT_h   = (u16*)(ws + 17006592);   // [384][384] (73,728 fl each)
    u16*   WslT_l   = (u16*)(ws + 17080320);
    u16*   WclT_h   = (u16*)(ws + 17154048);
    u16*   WclT_l   = (u16*)(ws + 17227776);   // end 17,301,504 fl
    (void)in_sizes; (void)n_in; (void)out_size; (void)ws_size;

    dim3 blk(256);

    // weight transpose+splits (tiny)
    wsplit_t<<<1152, blk, 0, stream>>>(Wq, WqT_h, WqT_l, HIDc, AHSc);
    wsplit_t<<<1152, blk, 0, stream>>>(Wk, WkT_h, WkT_l, HIDc, AHSc);
    wsplit_t<<<1152, blk, 0, stream>>>(Wv, WvT_h, WvT_l, HIDc, AHSc);
    wsplit_t<<<576,  blk, 0, stream>>>(Wsl, WslT_h, WslT_l, AHSc, AHSc);
    wsplit_t<<<576,  blk, 0, stream>>>(Wcl, WclT_h, WclT_l, AHSc, AHSc);
    split_bf16<<<288, blk, 0, stream>>>(pw, pw_h, pw_l, 73728);

    // QKV projections (fused into one launch via z; A = fp32 hidden, split in-kernel)
    GSet sq{hidden, WqT_h, WqT_l, bq, q,    0};
    GSet sk{hidden, WkT_h, WkT_l, bk, kbuf, 0};
    GSet sv{hidden, WvT_h, WvT_l, bv, vbuf, 0};
    gemm_mfma<<<dim3(3, 64, 3), blk, 0, stream>>>(sq, sk, sv, HIDc, AHSc);

    // separable conv: depthwise (fp32, in out-scratch) then pointwise MFMA GEMM
    dwconv_kernel<<<BS_TOT * HIDc / 256, blk, 0, stream>>>(hidden, dwk, dwT);
    GSet sp{dwT, pw_h, pw_l, sepb, ksout, 0};
    gemm_mfma<<<dim3(3, 64, 1), blk, 0, stream>>>(sp, sp, sp, HIDc, AHSc);

    // conv-attention path -> conv_out (fp32)
    convattn_kernel<<<dim3(BS_TOT), dim3(384), 0, stream>>>(ksout, q, vbuf, Wak, bak, conv_out);

    // V transpose/split for PV
    vt_split<<<dim3(32, 24), blk, 0, stream>>>(vbuf, vt_h, vt_l);

    // self-attention: scores (bf16x3 MFMA), softmax stats, PV (bf16x3 MFMA)
    scores_mfma<<<dim3(SLEN / 128, SLEN / 128, BB * NH), blk, 0, stream>>>(q, kbuf, mask, scores);
    rowstats_kernel<<<dim3(BB * NH * SLEN), blk, 0, stream>>>(scores, stats);
    pv_mfma<<<dim3(SLEN / 64, BB * NH), blk, 0, stream>>>(scores, stats, vt_h, vt_l, attn_out);

    // final mix: ctx = [attn_out@Wsl+bsl , conv_out@Wcl+bcl] (A fp32, split in-kernel)
    GSet so0{attn_out, WslT_h, WslT_l, bsl, ctx_out, 0};
    GSet so1{conv_out, WclT_h, WclT_l, bcl, ctx_out, HALFc};
    gemm_mfma<<<dim3(3, 64, 2), blk, 0, stream>>>(so0, so1, so0, AHSc, HIDc);
}